// Round 13
// baseline (178.311 us; speedup 1.0000x reference)
//
#include <hip/hip_runtime.h>
#include <cstdint>

#define DIM 768
#define SEQ 2048
#define NB 2
#define NH 16
#define HD 48
#define NROWS (NB*SEQ)   // 4096

typedef __attribute__((ext_vector_type(8))) short bf16x8;
typedef __attribute__((ext_vector_type(4))) float f32x4;
typedef __attribute__((ext_vector_type(16))) float f32x16;
typedef unsigned int u32;

__device__ __forceinline__ short f2bf(float f) {
    union { float f; uint32_t u; } v; v.f = f;
    uint32_t u = v.u;
    uint32_t r = (u + 0x7FFFu + ((u >> 16) & 1u)) >> 16;
    return (short)r;
}
__device__ __forceinline__ u32 cvtpk(float lo, float hi) {
    u32 r;
    asm("v_cvt_pk_bf16_f32 %0, %1, %2" : "=v"(r) : "v"(lo), "v"(hi));
    return r;
}

// async global->LDS, 16B per lane; LDS dest = wave-uniform base + lane*16
__device__ __forceinline__ void gload16(const short* g, short* l) {
    __builtin_amdgcn_global_load_lds(
        (const __attribute__((address_space(1))) void*)g,
        (__attribute__((address_space(3))) void*)l, 16, 0, 0);
}

// ---------------------------------------------------------------------------
// fp32 -> bf16 pre-convert: dst = xb | Wq | Wk | Wv | Wo (R5-verified).
// ---------------------------------------------------------------------------
__global__ __launch_bounds__(256)
void cvt_bf16(const float* __restrict__ x,  const float* __restrict__ wq,
              const float* __restrict__ wk, const float* __restrict__ wv,
              const float* __restrict__ wo, short* __restrict__ dst)
{
    const int XN4 = (NROWS*DIM)/4;
    const int WN4 = (DIM*DIM)/4;
    const int T4  = XN4 + 4*WN4;
    for (int i = blockIdx.x*blockDim.x + threadIdx.x; i < T4; i += gridDim.x*blockDim.x) {
        const float* src; int off;
        if (i < XN4) { src = x; off = i; }
        else {
            int j = i - XN4;
            int w = j / WN4, r = j - w*WN4;
            src = (w==0) ? wq : (w==1) ? wk : (w==2) ? wv : wo;
            off = r;
        }
        float4 v = *(const float4*)(src + (size_t)off*4);
        short4 s; s.x=f2bf(v.x); s.y=f2bf(v.y); s.z=f2bf(v.z); s.w=f2bf(v.w);
        *(short4*)(dst + (size_t)i*4) = s;
    }
}

// ---------------------------------------------------------------------------
// bf16 MFMA GEMM — R10-verified structure (global_load_lds + both-sides XOR
// swizzle, BK=64, 2 barriers/K-step), templated on M-tile. MT=64 everywhere
// now: QKV grid 1536 (6.00/CU), O-proj 512 (2.00/CU) — R12 evidence: more
// blocks/CU hides the vmcnt drain (O-proj 1->2 saved ~20us).
// C = A*B^T; fused-B n0 picks q/k/v slice.
// ---------------------------------------------------------------------------
template<int MT, bool OUT_F32>
__global__ __launch_bounds__(256)
void gemm_gl(const short* __restrict__ A, const short* __restrict__ B,
             void* __restrict__ C0v, void* __restrict__ C1v, void* __restrict__ C2v)
{
    __shared__ short As[MT*64];
    __shared__ short Bs[96*64];
    const int FM = MT/32;                      // wave M-frags (4 or 2)

    const int tid  = threadIdx.x;
    const int lane = tid & 63;
    const int wid  = tid >> 6;
    const int wr = wid >> 1, wc = wid & 1;
    const int m  = lane & 15, kb = lane >> 4;
    const int m0 = blockIdx.y * MT, n0 = blockIdx.x * 96;
    const int lr = lane >> 3, lsl = lane & 7;
    const int gsl = (lsl ^ lr) * 8;            // pre-swizzled source k-offset

    void* Cv = C0v;
    const int slice = n0 / DIM;
    if (slice == 1) Cv = C1v; else if (slice == 2) Cv = C2v;
    const int ncol0 = n0 - slice * DIM;

    f32x4 acc[FM][3];
#pragma unroll
    for (int i = 0; i < FM; ++i)
#pragma unroll
        for (int j = 0; j < 3; ++j) acc[i][j] = (f32x4){0.f,0.f,0.f,0.f};

    for (int kt = 0; kt < DIM/64; ++kt) {
        const int k0 = kt * 64;
        __syncthreads();                     // prior iter's frag reads done
#pragma unroll
        for (int i = 0; i < FM; ++i) {
            int r0 = wid*(MT/4) + i*8;
            gload16(&A[(size_t)(m0 + r0 + lr)*DIM + k0 + gsl], &As[r0*64]);
        }
#pragma unroll
        for (int i = 0; i < 3; ++i) {
            int r0 = wid*24 + i*8;
            gload16(&B[(size_t)(n0 + r0 + lr)*DIM + k0 + gsl], &Bs[r0*64]);
        }
        __syncthreads();                     // vmcnt drained -> tile ready

        bf16x8 af[2][FM], bfr[2][3];
#pragma unroll
        for (int t = 0; t < 2; ++t) {
            int sl = ((t*4 + kb) ^ (m & 7)) * 8;
#pragma unroll
            for (int f = 0; f < FM; ++f)
                af[t][f]  = *(const bf16x8*)&As[(wr*(MT/2) + f*16 + m)*64 + sl];
#pragma unroll
            for (int f = 0; f < 3; ++f)
                bfr[t][f] = *(const bf16x8*)&Bs[(wc*48 + f*16 + m)*64 + sl];
        }
#pragma unroll
        for (int fm = 0; fm < FM; ++fm)
#pragma unroll
            for (int fn = 0; fn < 3; ++fn) {
                acc[fm][fn] = __builtin_amdgcn_mfma_f32_16x16x32_bf16(af[0][fm], bfr[0][fn], acc[fm][fn], 0, 0, 0);
                acc[fm][fn] = __builtin_amdgcn_mfma_f32_16x16x32_bf16(af[1][fm], bfr[1][fn], acc[fm][fn], 0, 0, 0);
            }
    }

#pragma unroll
    for (int fm = 0; fm < FM; ++fm)
#pragma unroll
        for (int fn = 0; fn < 3; ++fn) {
            int col = ncol0 + wc*48 + fn*16 + m;
#pragma unroll
            for (int r = 0; r < 4; ++r) {
                int row = m0 + wr*(MT/2) + fm*16 + kb*4 + r;
                if (OUT_F32)
                    ((float*)Cv)[(size_t)row*DIM + col] = acc[fm][fn][r];
                else
                    ((short*)Cv)[(size_t)row*DIM + col] = f2bf(acc[fm][fn][r]);
            }
        }
}

// ---------------------------------------------------------------------------
// Flash attention v2 — EXACT R7/R10-verified kernel (77.5 us), untouched.
// (R12's KV-split regressed: dispatch 88.9 vs 77.5 — softmax VALU chain is
// the floor, not occupancy. Reverted per kill-criterion.)
// ---------------------------------------------------------------------------
__global__ __launch_bounds__(256)
void flash2(const short* __restrict__ Qb, const short* __restrict__ Kb,
            const short* __restrict__ Vb, short* __restrict__ Ctx)
{
    __shared__ short K_lds[64*64];
    __shared__ short Vt_lds[64*68];

    const int tid  = threadIdx.x;
    const int wid  = tid >> 6, lane = tid & 63;
    const int r    = lane & 31, hi = lane >> 5;
    const size_t base = (size_t)blockIdx.z*SEQ*DIM + (size_t)blockIdx.y*HD;
    const int q0 = blockIdx.x*128 + wid*32;
    const float C2  = 0.20823688f;   // 48^-0.5 * log2(e)
    const float THR = 11.5f;         // defer-max threshold (~8 nats)

    for (int i = tid; i < 16*68; i += 256) Vt_lds[48*68 + i] = 0;

    bf16x8 qf[3];
#pragma unroll
    for (int s = 0; s < 3; ++s)
        qf[s] = *(const bf16x8*)&Qb[base + (size_t)(q0 + r)*DIM + s*16 + hi*8];

    f32x16 z16;
#pragma unroll
    for (int i = 0; i < 16; ++i) z16[i] = 0.f;

    f32x16 acc0 = z16, acc1 = z16;
    float m_i = -1e30f, l_i = 0.f;

    const int row0 = tid >> 3,       ps0 = tid & 7;
    const int row1 = (tid+256) >> 3, ps1 = tid & 7;
    const int ls0 = ps0 ^ (row0 & 7), ls1 = ps1 ^ (row1 & 7);

    bf16x8 k0r, k1r; short vreg[12];
    k0r = *(const bf16x8*)&Kb[base + (size_t)row0*DIM + ls0*8];
    k1r = *(const bf16x8*)&Kb[base + (size_t)row1*DIM + ls1*8];
#pragma unroll
    for (int j = 0; j < 12; ++j)
        vreg[j] = Vb[base + (size_t)lane*DIM + wid*12 + j];

    for (int t = 0; t < SEQ/64; ++t) {
        __syncthreads();
        *(bf16x8*)&K_lds[row0*64 + ps0*8] = k0r;
        *(bf16x8*)&K_lds[row1*64 + ps1*8] = k1r;
#pragma unroll
        for (int j = 0; j < 12; ++j)
            Vt_lds[(wid*12 + j)*68 + lane] = vreg[j];
        __syncthreads();

        if (t + 1 < SEQ/64) {
            int c0 = (t+1)*64;
            k0r = *(const bf16x8*)&Kb[base + (size_t)(c0 + row0)*DIM + ls0*8];
            k1r = *(const bf16x8*)&Kb[base + (size_t)(c0 + row1)*DIM + ls1*8];
#pragma unroll
            for (int j = 0; j < 12; ++j)
                vreg[j] = Vb[base + (size_t)(c0 + lane)*DIM + wid*12 + j];
        }

        f32x16 sa[2];
#pragma unroll
        for (int ct = 0; ct < 2; ++ct) {
            f32x16 a = z16;
#pragma unroll
            for (int s = 0; s < 3; ++s) {
                int row = ct*32 + r;
                bf16x8 kf = *(const bf16x8*)&K_lds[row*64 + ((s*2+hi) ^ (row&7))*8];
                a = __builtin_amdgcn_mfma_f32_32x32x16_bf16(kf, qf[s], a, 0, 0, 0);
            }
            sa[ct] = a;
        }

        float mx = -1e30f;
#pragma unroll
        for (int ct = 0; ct < 2; ++ct)
#pragma unroll
            for (int i = 0; i < 16; ++i) mx = fmaxf(mx, sa[ct][i]);
        mx = fmaxf(mx, __shfl_xor(mx, 32));
        mx *= C2;

        float mn = m_i;
        if (!__all(mx - m_i <= THR)) {
            mn = fmaxf(m_i, mx);
            float al = exp2f(m_i - mn);
            l_i *= al;
#pragma unroll
            for (int i = 0; i < 16; ++i) { acc0[i] *= al; acc1[i] *= al; }
            m_i = mn;
        }

        float rs = 0.f;
        u32 w[2][8], sw[2][8];
#pragma unroll
        for (int ct = 0; ct < 2; ++ct)
#pragma unroll
            for (int k = 0; k < 8; ++k) {
                float p0 = exp2f(fmaf(sa[ct][2*k],   C2, -mn));
                float p1 = exp2f(fmaf(sa[ct][2*k+1], C2, -mn));
                w[ct][k] = cvtpk(p0, p1);
                rs += p0 + p1;
            }
        rs += __shfl_xor(rs, 32);
        l_i += rs;
#pragma unroll
        for (int ct = 0; ct < 2; ++ct)
#pragma unroll
            for (int k = 0; k < 8; ++k) sw[ct][k] = (u32)__shfl_xor((int)w[ct][k], 32);

#pragma unroll
        for (int ct = 0; ct < 2; ++ct)
#pragma unroll
            for (int hf = 0; hf < 2; ++hf) {
                u32 f0 = hi ? sw[ct][4*hf+2] : w[ct][4*hf+0];
                u32 f1 = hi ? sw[ct][4*hf+3] : w[ct][4*hf+1];
                u32 f2 = hi ? w[ct][4*hf+2]  : sw[ct][4*hf+0];
                u32 f3 = hi ? w[ct][4*hf+3]  : sw[ct][4*hf+1];
                int4 pw = make_int4((int)f0, (int)f1, (int)f2, (int)f3);
                bf16x8 pb = __builtin_bit_cast(bf16x8, pw);
#pragma unroll
                for (int dt = 0; dt < 2; ++dt) {
                    int off = (dt*32 + r)*68 + ct*32 + hf*16 + hi*8;
                    short4 v0 = *(const short4*)&Vt_lds[off];
                    short4 v1 = *(const short4*)&Vt_lds[off + 4];
                    bf16x8 av = {v0.x, v0.y, v0.z, v0.w, v1.x, v1.y, v1.z, v1.w};
                    if (dt == 0) acc0 = __builtin_amdgcn_mfma_f32_32x32x16_bf16(av, pb, acc0, 0, 0, 0);
                    else         acc1 = __builtin_amdgcn_mfma_f32_32x32x16_bf16(av, pb, acc1, 0, 0, 0);
                }
            }
    }

    float inv = 1.0f / l_i;
#pragma unroll
    for (int g = 0; g < 16; ++g) {
        int d = (g&3) + 8*(g>>2) + 4*hi;
        Ctx[base + (size_t)(q0 + r)*DIM + d] = f2bf(acc0[g] * inv);
    }
#pragma unroll
    for (int g = 0; g < 8; ++g) {
        int d = 32 + (g&3) + 8*(g>>2) + 4*hi;
        Ctx[base + (size_t)(q0 + r)*DIM + d] = f2bf(acc1[g] * inv);
    }
}

extern "C" void kernel_launch(void* const* d_in, const int* in_sizes, int n_in,
                              void* d_out, int out_size, void* d_ws, size_t ws_size,
                              hipStream_t stream)
{
    const float* x  = (const float*)d_in[0];
    const float* Wq = (const float*)d_in[1];
    const float* Wk = (const float*)d_in[2];
    const float* Wv = (const float*)d_in[3];
    const float* Wo = (const float*)d_in[4];
    float* out = (float*)d_out;

    const size_t XN = (size_t)NROWS * DIM;
    const size_t WN = (size_t)DIM * DIM;

    short* xb   = (short*)d_ws;
    short* wcat = xb   + XN;                 // [2304][768] = Wq|Wk|Wv
    short* wob  = wcat + 3*WN;
    short* qb   = wob  + WN;
    short* kbuf = qb   + XN;
    short* vbuf = kbuf + XN;
    short* ctxb = vbuf + XN;                 // ~29 MB total

    cvt_bf16<<<1024, 256, 0, stream>>>(x, Wq, Wk, Wv, Wo, xb);

    dim3 g1(3*DIM/96, NROWS/64, 1);          // 24 x 64 = 1536 blocks (6.00/CU)
    gemm_gl<64, false><<<g1, 256, 0, stream>>>(xb, wcat, qb, kbuf, vbuf);

    dim3 g2(SEQ/128, NH, NB);                // 512 blocks
    flash2<<<g2, 256, 0, stream>>>(qb, kbuf, vbuf, ctxb);

    dim3 g3(DIM/96, NROWS/64, 1);            // 8 x 64 = 512 blocks (2.00/CU)
    gemm_gl<64, true><<<g3, 256, 0, stream>>>(ctxb, wob, out, out, out);
}

// Round 14
// 170.211 us; speedup vs baseline: 1.0476x; 1.0476x over previous
//
#include <hip/hip_runtime.h>
#include <cstdint>

#define DIM 768
#define SEQ 2048
#define NB 2
#define NH 16
#define HD 48
#define NROWS (NB*SEQ)   // 4096

typedef __attribute__((ext_vector_type(8))) short bf16x8;
typedef __attribute__((ext_vector_type(4))) float f32x4;
typedef __attribute__((ext_vector_type(16))) float f32x16;
typedef unsigned int u32;

__device__ __forceinline__ short f2bf(float f) {
    union { float f; uint32_t u; } v; v.f = f;
    uint32_t u = v.u;
    uint32_t r = (u + 0x7FFFu + ((u >> 16) & 1u)) >> 16;
    return (short)r;
}
__device__ __forceinline__ u32 cvtpk(float lo, float hi) {
    u32 r;
    asm("v_cvt_pk_bf16_f32 %0, %1, %2" : "=v"(r) : "v"(lo), "v"(hi));
    return r;
}

// async global->LDS, 16B per lane; LDS dest = wave-uniform base + lane*16
__device__ __forceinline__ void gload16(const short* g, short* l) {
    __builtin_amdgcn_global_load_lds(
        (const __attribute__((address_space(1))) void*)g,
        (__attribute__((address_space(3))) void*)l, 16, 0, 0);
}

// ---------------------------------------------------------------------------
// fp32 -> bf16 pre-convert: dst = xb | Wq | Wk | Wv | Wo (R5-verified, ~8us).
// ---------------------------------------------------------------------------
__global__ __launch_bounds__(256)
void cvt_bf16(const float* __restrict__ x,  const float* __restrict__ wq,
              const float* __restrict__ wk, const float* __restrict__ wv,
              const float* __restrict__ wo, short* __restrict__ dst)
{
    const int XN4 = (NROWS*DIM)/4;
    const int WN4 = (DIM*DIM)/4;
    const int T4  = XN4 + 4*WN4;
    for (int i = blockIdx.x*blockDim.x + threadIdx.x; i < T4; i += gridDim.x*blockDim.x) {
        const float* src; int off;
        if (i < XN4) { src = x; off = i; }
        else {
            int j = i - XN4;
            int w = j / WN4, r = j - w*WN4;
            src = (w==0) ? wq : (w==1) ? wk : (w==2) ? wv : wo;
            off = r;
        }
        float4 v = *(const float4*)(src + (size_t)off*4);
        short4 s; s.x=f2bf(v.x); s.y=f2bf(v.y); s.z=f2bf(v.z); s.w=f2bf(v.w);
        *(short4*)(dst + (size_t)i*4) = s;
    }
}

// ---------------------------------------------------------------------------
// bf16 MFMA GEMM — R10-verified structure (global_load_lds + both-sides XOR
// swizzle, BK=64, 2 barriers/K-step), templated on M-tile.
// Measured component costs: QKV MT=128 ~66us (MT=64 was 84 — B-staging
// doubles, R13); O-proj MT=64 ~10us (MT=128 @1/CU was 22 — R12).
// C = A*B^T; fused-B n0 picks q/k/v slice.
// ---------------------------------------------------------------------------
template<int MT, bool OUT_F32>
__global__ __launch_bounds__(256)
void gemm_gl(const short* __restrict__ A, const short* __restrict__ B,
             void* __restrict__ C0v, void* __restrict__ C1v, void* __restrict__ C2v)
{
    __shared__ short As[MT*64];
    __shared__ short Bs[96*64];
    const int FM = MT/32;                      // wave M-frags (4 or 2)

    const int tid  = threadIdx.x;
    const int lane = tid & 63;
    const int wid  = tid >> 6;
    const int wr = wid >> 1, wc = wid & 1;
    const int m  = lane & 15, kb = lane >> 4;
    const int m0 = blockIdx.y * MT, n0 = blockIdx.x * 96;
    const int lr = lane >> 3, lsl = lane & 7;
    const int gsl = (lsl ^ lr) * 8;            // pre-swizzled source k-offset

    void* Cv = C0v;
    const int slice = n0 / DIM;
    if (slice == 1) Cv = C1v; else if (slice == 2) Cv = C2v;
    const int ncol0 = n0 - slice * DIM;

    f32x4 acc[FM][3];
#pragma unroll
    for (int i = 0; i < FM; ++i)
#pragma unroll
        for (int j = 0; j < 3; ++j) acc[i][j] = (f32x4){0.f,0.f,0.f,0.f};

    for (int kt = 0; kt < DIM/64; ++kt) {
        const int k0 = kt * 64;
        __syncthreads();                     // prior iter's frag reads done
#pragma unroll
        for (int i = 0; i < FM; ++i) {
            int r0 = wid*(MT/4) + i*8;
            gload16(&A[(size_t)(m0 + r0 + lr)*DIM + k0 + gsl], &As[r0*64]);
        }
#pragma unroll
        for (int i = 0; i < 3; ++i) {
            int r0 = wid*24 + i*8;
            gload16(&B[(size_t)(n0 + r0 + lr)*DIM + k0 + gsl], &Bs[r0*64]);
        }
        __syncthreads();                     // vmcnt drained -> tile ready

        bf16x8 af[2][FM], bfr[2][3];
#pragma unroll
        for (int t = 0; t < 2; ++t) {
            int sl = ((t*4 + kb) ^ (m & 7)) * 8;
#pragma unroll
            for (int f = 0; f < FM; ++f)
                af[t][f]  = *(const bf16x8*)&As[(wr*(MT/2) + f*16 + m)*64 + sl];
#pragma unroll
            for (int f = 0; f < 3; ++f)
                bfr[t][f] = *(const bf16x8*)&Bs[(wc*48 + f*16 + m)*64 + sl];
        }
#pragma unroll
        for (int fm = 0; fm < FM; ++fm)
#pragma unroll
            for (int fn = 0; fn < 3; ++fn) {
                acc[fm][fn] = __builtin_amdgcn_mfma_f32_16x16x32_bf16(af[0][fm], bfr[0][fn], acc[fm][fn], 0, 0, 0);
                acc[fm][fn] = __builtin_amdgcn_mfma_f32_16x16x32_bf16(af[1][fm], bfr[1][fn], acc[fm][fn], 0, 0, 0);
            }
    }

#pragma unroll
    for (int fm = 0; fm < FM; ++fm)
#pragma unroll
        for (int fn = 0; fn < 3; ++fn) {
            int col = ncol0 + wc*48 + fn*16 + m;
#pragma unroll
            for (int r = 0; r < 4; ++r) {
                int row = m0 + wr*(MT/2) + fm*16 + kb*4 + r;
                if (OUT_F32)
                    ((float*)Cv)[(size_t)row*DIM + col] = acc[fm][fn][r];
                else
                    ((short*)Cv)[(size_t)row*DIM + col] = f2bf(acc[fm][fn][r]);
            }
        }
}

// ---------------------------------------------------------------------------
// Flash attention v2 — EXACT R7/R10/R13-verified kernel (76.5-77.5 us).
// ---------------------------------------------------------------------------
__global__ __launch_bounds__(256)
void flash2(const short* __restrict__ Qb, const short* __restrict__ Kb,
            const short* __restrict__ Vb, short* __restrict__ Ctx)
{
    __shared__ short K_lds[64*64];
    __shared__ short Vt_lds[64*68];

    const int tid  = threadIdx.x;
    const int wid  = tid >> 6, lane = tid & 63;
    const int r    = lane & 31, hi = lane >> 5;
    const size_t base = (size_t)blockIdx.z*SEQ*DIM + (size_t)blockIdx.y*HD;
    const int q0 = blockIdx.x*128 + wid*32;
    const float C2  = 0.20823688f;   // 48^-0.5 * log2(e)
    const float THR = 11.5f;         // defer-max threshold (~8 nats)

    for (int i = tid; i < 16*68; i += 256) Vt_lds[48*68 + i] = 0;

    bf16x8 qf[3];
#pragma unroll
    for (int s = 0; s < 3; ++s)
        qf[s] = *(const bf16x8*)&Qb[base + (size_t)(q0 + r)*DIM + s*16 + hi*8];

    f32x16 z16;
#pragma unroll
    for (int i = 0; i < 16; ++i) z16[i] = 0.f;

    f32x16 acc0 = z16, acc1 = z16;
    float m_i = -1e30f, l_i = 0.f;

    const int row0 = tid >> 3,       ps0 = tid & 7;
    const int row1 = (tid+256) >> 3, ps1 = tid & 7;
    const int ls0 = ps0 ^ (row0 & 7), ls1 = ps1 ^ (row1 & 7);

    bf16x8 k0r, k1r; short vreg[12];
    k0r = *(const bf16x8*)&Kb[base + (size_t)row0*DIM + ls0*8];
    k1r = *(const bf16x8*)&Kb[base + (size_t)row1*DIM + ls1*8];
#pragma unroll
    for (int j = 0; j < 12; ++j)
        vreg[j] = Vb[base + (size_t)lane*DIM + wid*12 + j];

    for (int t = 0; t < SEQ/64; ++t) {
        __syncthreads();
        *(bf16x8*)&K_lds[row0*64 + ps0*8] = k0r;
        *(bf16x8*)&K_lds[row1*64 + ps1*8] = k1r;
#pragma unroll
        for (int j = 0; j < 12; ++j)
            Vt_lds[(wid*12 + j)*68 + lane] = vreg[j];
        __syncthreads();

        if (t + 1 < SEQ/64) {
            int c0 = (t+1)*64;
            k0r = *(const bf16x8*)&Kb[base + (size_t)(c0 + row0)*DIM + ls0*8];
            k1r = *(const bf16x8*)&Kb[base + (size_t)(c0 + row1)*DIM + ls1*8];
#pragma unroll
            for (int j = 0; j < 12; ++j)
                vreg[j] = Vb[base + (size_t)(c0 + lane)*DIM + wid*12 + j];
        }

        f32x16 sa[2];
#pragma unroll
        for (int ct = 0; ct < 2; ++ct) {
            f32x16 a = z16;
#pragma unroll
            for (int s = 0; s < 3; ++s) {
                int row = ct*32 + r;
                bf16x8 kf = *(const bf16x8*)&K_lds[row*64 + ((s*2+hi) ^ (row&7))*8];
                a = __builtin_amdgcn_mfma_f32_32x32x16_bf16(kf, qf[s], a, 0, 0, 0);
            }
            sa[ct] = a;
        }

        float mx = -1e30f;
#pragma unroll
        for (int ct = 0; ct < 2; ++ct)
#pragma unroll
            for (int i = 0; i < 16; ++i) mx = fmaxf(mx, sa[ct][i]);
        mx = fmaxf(mx, __shfl_xor(mx, 32));
        mx *= C2;

        float mn = m_i;
        if (!__all(mx - m_i <= THR)) {
            mn = fmaxf(m_i, mx);
            float al = exp2f(m_i - mn);
            l_i *= al;
#pragma unroll
            for (int i = 0; i < 16; ++i) { acc0[i] *= al; acc1[i] *= al; }
            m_i = mn;
        }

        float rs = 0.f;
        u32 w[2][8], sw[2][8];
#pragma unroll
        for (int ct = 0; ct < 2; ++ct)
#pragma unroll
            for (int k = 0; k < 8; ++k) {
                float p0 = exp2f(fmaf(sa[ct][2*k],   C2, -mn));
                float p1 = exp2f(fmaf(sa[ct][2*k+1], C2, -mn));
                w[ct][k] = cvtpk(p0, p1);
                rs += p0 + p1;
            }
        rs += __shfl_xor(rs, 32);
        l_i += rs;
#pragma unroll
        for (int ct = 0; ct < 2; ++ct)
#pragma unroll
            for (int k = 0; k < 8; ++k) sw[ct][k] = (u32)__shfl_xor((int)w[ct][k], 32);

#pragma unroll
        for (int ct = 0; ct < 2; ++ct)
#pragma unroll
            for (int hf = 0; hf < 2; ++hf) {
                u32 f0 = hi ? sw[ct][4*hf+2] : w[ct][4*hf+0];
                u32 f1 = hi ? sw[ct][4*hf+3] : w[ct][4*hf+1];
                u32 f2 = hi ? w[ct][4*hf+2]  : sw[ct][4*hf+0];
                u32 f3 = hi ? w[ct][4*hf+3]  : sw[ct][4*hf+1];
                int4 pw = make_int4((int)f0, (int)f1, (int)f2, (int)f3);
                bf16x8 pb = __builtin_bit_cast(bf16x8, pw);
#pragma unroll
                for (int dt = 0; dt < 2; ++dt) {
                    int off = (dt*32 + r)*68 + ct*32 + hf*16 + hi*8;
                    short4 v0 = *(const short4*)&Vt_lds[off];
                    short4 v1 = *(const short4*)&Vt_lds[off + 4];
                    bf16x8 av = {v0.x, v0.y, v0.z, v0.w, v1.x, v1.y, v1.z, v1.w};
                    if (dt == 0) acc0 = __builtin_amdgcn_mfma_f32_32x32x16_bf16(av, pb, acc0, 0, 0, 0);
                    else         acc1 = __builtin_amdgcn_mfma_f32_32x32x16_bf16(av, pb, acc1, 0, 0, 0);
                }
            }
    }

    float inv = 1.0f / l_i;
#pragma unroll
    for (int g = 0; g < 16; ++g) {
        int d = (g&3) + 8*(g>>2) + 4*hi;
        Ctx[base + (size_t)(q0 + r)*DIM + d] = f2bf(acc0[g] * inv);
    }
#pragma unroll
    for (int g = 0; g < 8; ++g) {
        int d = 32 + (g&3) + 8*(g>>2) + 4*hi;
        Ctx[base + (size_t)(q0 + r)*DIM + d] = f2bf(acc1[g] * inv);
    }
}

extern "C" void kernel_launch(void* const* d_in, const int* in_sizes, int n_in,
                              void* d_out, int out_size, void* d_ws, size_t ws_size,
                              hipStream_t stream)
{
    const float* x  = (const float*)d_in[0];
    const float* Wq = (const float*)d_in[1];
    const float* Wk = (const float*)d_in[2];
    const float* Wv = (const float*)d_in[3];
    const float* Wo = (const float*)d_in[4];
    float* out = (float*)d_out;

    const size_t XN = (size_t)NROWS * DIM;
    const size_t WN = (size_t)DIM * DIM;

    short* xb   = (short*)d_ws;
    short* wcat = xb   + XN;                 // [2304][768] = Wq|Wk|Wv
    short* wob  = wcat + 3*WN;
    short* qb   = wob  + WN;
    short* kbuf = qb   + XN;
    short* vbuf = kbuf + XN;
    short* ctxb = vbuf + XN;                 // ~29 MB total

    cvt_bf16<<<1024, 256, 0, stream>>>(x, Wq, Wk, Wv, Wo, xb);

    dim3 g1(3*DIM/96, NROWS/128, 1);         // 24 x 32 = 768 blocks (3.00/CU)
    gemm_gl<128, false><<<g1, 256, 0, stream>>>(xb, wcat, qb, kbuf, vbuf);

    dim3 g2(SEQ/128, NH, NB);                // 512 blocks
    flash2<<<g2, 256, 0, stream>>>(qb, kbuf, vbuf, ctxb);

    dim3 g3(DIM/96, NROWS/64, 1);            // 8 x 64 = 512 blocks (2.00/CU)
    gemm_gl<64, true><<<g3, 256, 0, stream>>>(ctxb, wob, out, out, out);
}